// Round 1
// baseline (30002.344 us; speedup 1.0000x reference)
//
#include <hip/hip_runtime.h>
#include <cstddef>

// ---------------------------------------------------------------------------
// CLIP ViT-B/16 visual tower, fp32 baseline.
// B=32, S=197, D=768, H=12, HD=64, F=3072, L=12, O=512
// ---------------------------------------------------------------------------

#define Bv   32
#define Sv   197
#define Dv   768
#define Hh   12
#define HDv  64
#define Fv   3072
#define Lv   12
#define Ov   512
#define TOK  (Bv * Sv)        // 6304
#define NPATCH 196

// ---------------------------------------------------------------------------
// block-wide (256 thread) reduction of two scalars
// ---------------------------------------------------------------------------
__device__ __forceinline__ void reduce2_256(float& s1, float& s2) {
    #pragma unroll
    for (int off = 32; off > 0; off >>= 1) {
        s1 += __shfl_down(s1, off, 64);
        s2 += __shfl_down(s2, off, 64);
    }
    __shared__ float r1[4], r2[4];
    int lane = threadIdx.x & 63, w = threadIdx.x >> 6;
    if (lane == 0) { r1[w] = s1; r2[w] = s2; }
    __syncthreads();
    s1 = r1[0] + r1[1] + r1[2] + r1[3];
    s2 = r2[0] + r2[1] + r2[2] + r2[3];
    __syncthreads();
}

// ---------------------------------------------------------------------------
// im2col + normalize: images [B,3,224,224] -> P [B*196, 768]
// col = c*256 + kh*16 + kw  (matches conv_w [768, 3*16*16] row-major)
// ---------------------------------------------------------------------------
__global__ void im2col_kernel(const float* __restrict__ img, float* __restrict__ out) {
    int idx = blockIdx.x * 256 + threadIdx.x;          // < 6272*768
    int col = idx % 768;
    int row = idx / 768;
    int b = row / NPATCH, p = row % NPATCH;
    int ph = p / 14, pw = p % 14;
    int c  = col >> 8;
    int r  = col & 255;
    int kh = r >> 4, kw = r & 15;
    int y = ph * 16 + kh, x = pw * 16 + kw;
    const float mean[3] = {0.48145466f, 0.4578275f, 0.40821073f};
    const float stdv[3] = {0.26862954f, 0.26130258f, 0.27577711f};
    float v = img[((size_t)(b * 3 + c) * 224 + y) * 224 + x];
    out[idx] = (v - mean[c]) / stdv[c];
}

// ---------------------------------------------------------------------------
// Tiled fp32 GEMM: C[m,n] = sum_k A[m,k] * W[n,k] (+bias) (+res) (QuickGELU)
// A row-major [M,K], W row-major [N,K]. 64x64 tile, TK=16, 256 threads, 4x4.
// N % 64 == 0, K % 16 == 0; M guarded.
// ---------------------------------------------------------------------------
template <int ACT>
__global__ __launch_bounds__(256) void gemm_nt(
        const float* __restrict__ A, const float* __restrict__ W,
        const float* __restrict__ bias, const float* __restrict__ res,
        float* __restrict__ C, int M, int N, int K) {
    __shared__ float As[16][65];
    __shared__ float Ws[16][65];
    int tid = threadIdx.x;
    int tx = tid & 15, ty = tid >> 4;
    int m0 = blockIdx.y * 64, n0 = blockIdx.x * 64;
    int lr = tid >> 2;          // 0..63
    int lk = (tid & 3) * 4;     // 0,4,8,12

    float c[4][4] = {};
    const float* Ap = A + (size_t)(m0 + lr) * K + lk;
    const float* Wp = W + (size_t)(n0 + lr) * K + lk;
    bool aval = (m0 + lr) < M;

    for (int k0 = 0; k0 < K; k0 += 16) {
        float4 av = aval ? *(const float4*)(Ap + k0) : make_float4(0.f, 0.f, 0.f, 0.f);
        float4 wv = *(const float4*)(Wp + k0);
        __syncthreads();
        As[lk + 0][lr] = av.x; As[lk + 1][lr] = av.y;
        As[lk + 2][lr] = av.z; As[lk + 3][lr] = av.w;
        Ws[lk + 0][lr] = wv.x; Ws[lk + 1][lr] = wv.y;
        Ws[lk + 2][lr] = wv.z; Ws[lk + 3][lr] = wv.w;
        __syncthreads();
        #pragma unroll
        for (int kk = 0; kk < 16; kk++) {
            float a0 = As[kk][ty * 4 + 0], a1 = As[kk][ty * 4 + 1];
            float a2 = As[kk][ty * 4 + 2], a3 = As[kk][ty * 4 + 3];
            float b0 = Ws[kk][tx * 4 + 0], b1 = Ws[kk][tx * 4 + 1];
            float b2 = Ws[kk][tx * 4 + 2], b3 = Ws[kk][tx * 4 + 3];
            c[0][0] += a0 * b0; c[0][1] += a0 * b1; c[0][2] += a0 * b2; c[0][3] += a0 * b3;
            c[1][0] += a1 * b0; c[1][1] += a1 * b1; c[1][2] += a1 * b2; c[1][3] += a1 * b3;
            c[2][0] += a2 * b0; c[2][1] += a2 * b1; c[2][2] += a2 * b2; c[2][3] += a2 * b3;
            c[3][0] += a3 * b0; c[3][1] += a3 * b1; c[3][2] += a3 * b2; c[3][3] += a3 * b3;
        }
    }

    float bn[4];
    #pragma unroll
    for (int j = 0; j < 4; j++) bn[j] = bias ? bias[n0 + tx * 4 + j] : 0.f;

    #pragma unroll
    for (int i = 0; i < 4; i++) {
        int m = m0 + ty * 4 + i;
        if (m >= M) continue;
        size_t base = (size_t)m * N + n0 + tx * 4;
        #pragma unroll
        for (int j = 0; j < 4; j++) {
            float v = c[i][j] + bn[j];
            if (res) v += res[base + j];
            if (ACT == 1) v = v * (1.0f / (1.0f + __expf(-1.702f * v)));
            C[base + j] = v;
        }
    }
}

// ---------------------------------------------------------------------------
// LayerNorm over last dim (768). One block (256 thr) per token.
// ---------------------------------------------------------------------------
__global__ void ln_kernel(const float* __restrict__ in, float* __restrict__ out,
                          const float* __restrict__ s, const float* __restrict__ b) {
    int t = blockIdx.x;
    const float* row = in + (size_t)t * Dv;
    int tid = threadIdx.x;
    float v[3], s1 = 0.f, s2 = 0.f;
    #pragma unroll
    for (int i = 0; i < 3; i++) {
        v[i] = row[tid + 256 * i];
        s1 += v[i]; s2 += v[i] * v[i];
    }
    reduce2_256(s1, s2);
    float mean = s1 * (1.0f / Dv);
    float var  = s2 * (1.0f / Dv) - mean * mean;
    float rstd = rsqrtf(var + 1e-5f);
    float* orow = out + (size_t)t * Dv;
    #pragma unroll
    for (int i = 0; i < 3; i++) {
        int d = tid + 256 * i;
        orow[d] = (v[i] - mean) * rstd * s[d] + b[d];
    }
}

// ---------------------------------------------------------------------------
// embed (cls/patch + pos) + ln_pre -> x. One block per token.
// ---------------------------------------------------------------------------
__global__ void embed_ln_kernel(const float* __restrict__ conv_out,
                                const float* __restrict__ cls,
                                const float* __restrict__ pos,
                                const float* __restrict__ s,
                                const float* __restrict__ b,
                                float* __restrict__ x) {
    int t = blockIdx.x;                 // b*197 + si
    int bb = t / Sv, si = t % Sv;
    int tid = threadIdx.x;
    float v[3], s1 = 0.f, s2 = 0.f;
    #pragma unroll
    for (int i = 0; i < 3; i++) {
        int d = tid + 256 * i;
        float e = (si == 0) ? cls[d]
                            : conv_out[((size_t)bb * NPATCH + (si - 1)) * Dv + d];
        v[i] = e + pos[(size_t)si * Dv + d];
        s1 += v[i]; s2 += v[i] * v[i];
    }
    reduce2_256(s1, s2);
    float mean = s1 * (1.0f / Dv);
    float var  = s2 * (1.0f / Dv) - mean * mean;
    float rstd = rsqrtf(var + 1e-5f);
    float* orow = x + (size_t)t * Dv;
    #pragma unroll
    for (int i = 0; i < 3; i++) {
        int d = tid + 256 * i;
        orow[d] = (v[i] - mean) * rstd * s[d] + b[d];
    }
}

// ---------------------------------------------------------------------------
// Attention: one wave (64 thr) per (q, h, b). qkv [TOK, 2304] packed q|k|v,
// each [H=12, HD=64]. Writes o [TOK, 768] with D index = h*64+hd.
// ---------------------------------------------------------------------------
__global__ __launch_bounds__(64) void attn_kernel(const float* __restrict__ qkv,
                                                  float* __restrict__ o) {
    int qi = blockIdx.x, h = blockIdx.y, b = blockIdx.z;
    int t = threadIdx.x;
    __shared__ float qs[64];
    __shared__ float sc[200];

    size_t rowq = ((size_t)(b * Sv + qi)) * 2304 + h * 64;
    qs[t] = qkv[rowq + t] * 0.125f;    // HD^-0.5
    __syncthreads();

    float sv[4];
    float smax = -1e30f;
    #pragma unroll
    for (int jj = 0; jj < 4; jj++) {
        int j = t + jj * 64;
        float acc = -1e30f;
        if (j < Sv) {
            const float* kr = qkv + ((size_t)(b * Sv + j)) * 2304 + Dv + h * 64;
            acc = 0.f;
            #pragma unroll 8
            for (int d = 0; d < 64; d++) acc += qs[d] * kr[d];
        }
        sv[jj] = acc;
        smax = fmaxf(smax, acc);
    }
    #pragma unroll
    for (int off = 32; off > 0; off >>= 1)
        smax = fmaxf(smax, __shfl_xor(smax, off, 64));

    float ssum = 0.f;
    #pragma unroll
    for (int jj = 0; jj < 4; jj++) {
        int j = t + jj * 64;
        if (j < Sv) {
            float p = __expf(sv[jj] - smax);
            sc[j] = p;
            ssum += p;
        }
    }
    #pragma unroll
    for (int off = 32; off > 0; off >>= 1)
        ssum += __shfl_xor(ssum, off, 64);
    __syncthreads();

    float inv = 1.0f / ssum;
    float acc = 0.f;
    for (int j = 0; j < Sv; j++) {
        const float* vr = qkv + ((size_t)(b * Sv + j)) * 2304 + 2 * Dv + h * 64;
        acc += sc[j] * vr[t];
    }
    o[((size_t)(b * Sv + qi)) * Dv + h * 64 + t] = acc * inv;
}

// ---------------------------------------------------------------------------
// Head: ln_post on cls token + @ vis_proj [768,512]. One block per batch.
// ---------------------------------------------------------------------------
__global__ void head_kernel(const float* __restrict__ x,
                            const float* __restrict__ s, const float* __restrict__ b,
                            const float* __restrict__ vp, float* __restrict__ out) {
    int bb = blockIdx.x, tid = threadIdx.x;
    __shared__ float xn[Dv];
    const float* row = x + (size_t)(bb * Sv) * Dv;   // cls token
    float v[3], s1 = 0.f, s2 = 0.f;
    #pragma unroll
    for (int i = 0; i < 3; i++) {
        v[i] = row[tid + 256 * i];
        s1 += v[i]; s2 += v[i] * v[i];
    }
    reduce2_256(s1, s2);
    float mean = s1 * (1.0f / Dv);
    float var  = s2 * (1.0f / Dv) - mean * mean;
    float rstd = rsqrtf(var + 1e-5f);
    #pragma unroll
    for (int i = 0; i < 3; i++) {
        int d = tid + 256 * i;
        xn[d] = (v[i] - mean) * rstd * s[d] + b[d];
    }
    __syncthreads();
    float acc0 = 0.f, acc1 = 0.f;
    for (int d = 0; d < Dv; d++) {
        float xv = xn[d];
        acc0 += xv * vp[(size_t)d * Ov + tid];
        acc1 += xv * vp[(size_t)d * Ov + tid + 256];
    }
    out[(size_t)bb * Ov + tid]       = acc0;
    out[(size_t)bb * Ov + tid + 256] = acc1;
}

// ---------------------------------------------------------------------------
extern "C" void kernel_launch(void* const* d_in, const int* in_sizes, int n_in,
                              void* d_out, int out_size, void* d_ws, size_t ws_size,
                              hipStream_t stream) {
    const float* images   = (const float*)d_in[0];
    const float* conv_w   = (const float*)d_in[1];
    const float* cls_emb  = (const float*)d_in[2];
    const float* pos_emb  = (const float*)d_in[3];
    const float* lnpre_s  = (const float*)d_in[4];
    const float* lnpre_b  = (const float*)d_in[5];
    const float* ln1_s    = (const float*)d_in[6];
    const float* ln1_b    = (const float*)d_in[7];
    const float* qkv_w    = (const float*)d_in[8];
    const float* qkv_b    = (const float*)d_in[9];
    const float* out_w    = (const float*)d_in[10];
    const float* out_b    = (const float*)d_in[11];
    const float* ln2_s    = (const float*)d_in[12];
    const float* ln2_b    = (const float*)d_in[13];
    const float* fc_w     = (const float*)d_in[14];
    const float* fc_b     = (const float*)d_in[15];
    const float* proj_w   = (const float*)d_in[16];
    const float* proj_b   = (const float*)d_in[17];
    const float* lnpost_s = (const float*)d_in[18];
    const float* lnpost_b = (const float*)d_in[19];
    const float* vis_proj = (const float*)d_in[20];
    float* out = (float*)d_out;

    float* ws   = (float*)d_ws;
    float* x    = ws;                              // [6304, 768]
    float* abuf = x    + (size_t)TOK * Dv;         // [6304, 768]
    float* qkv  = abuf + (size_t)TOK * Dv;         // [6304, 2304] (also im2col)
    float* hbuf = qkv  + (size_t)TOK * 3 * Dv;     // [6304, 3072]

    // patch embedding
    im2col_kernel<<<(Bv * NPATCH * Dv) / 256, 256, 0, stream>>>(images, qkv);
    gemm_nt<0><<<dim3(Dv / 64, (Bv * NPATCH) / 64), 256, 0, stream>>>(
        qkv, conv_w, nullptr, nullptr, abuf, Bv * NPATCH, Dv, Dv);
    embed_ln_kernel<<<TOK, 256, 0, stream>>>(abuf, cls_emb, pos_emb,
                                             lnpre_s, lnpre_b, x);

    const int GM = (TOK + 63) / 64;   // 99
    for (int l = 0; l < Lv; l++) {
        ln_kernel<<<TOK, 256, 0, stream>>>(x, abuf, ln1_s + l * Dv, ln1_b + l * Dv);
        gemm_nt<0><<<dim3((3 * Dv) / 64, GM), 256, 0, stream>>>(
            abuf, qkv_w + (size_t)l * 3 * Dv * Dv, qkv_b + (size_t)l * 3 * Dv,
            nullptr, qkv, TOK, 3 * Dv, Dv);
        attn_kernel<<<dim3(Sv, Hh, Bv), 64, 0, stream>>>(qkv, abuf);
        gemm_nt<0><<<dim3(Dv / 64, GM), 256, 0, stream>>>(
            abuf, out_w + (size_t)l * Dv * Dv, out_b + (size_t)l * Dv,
            x, x, TOK, Dv, Dv);
        ln_kernel<<<TOK, 256, 0, stream>>>(x, abuf, ln2_s + l * Dv, ln2_b + l * Dv);
        gemm_nt<1><<<dim3(Fv / 64, GM), 256, 0, stream>>>(
            abuf, fc_w + (size_t)l * Fv * Dv, fc_b + (size_t)l * Fv,
            nullptr, hbuf, TOK, Fv, Dv);
        gemm_nt<0><<<dim3(Dv / 64, GM), 256, 0, stream>>>(
            hbuf, proj_w + (size_t)l * Dv * Fv, proj_b + (size_t)l * Dv,
            x, x, TOK, Dv, Fv);
    }

    head_kernel<<<Bv, 256, 0, stream>>>(x, lnpost_s, lnpost_b, vis_proj, out);
}

// Round 2
// 9382.400 us; speedup vs baseline: 3.1977x; 3.1977x over previous
//
#include <hip/hip_runtime.h>
#include <cstddef>

#define Bv   32
#define Sv   197
#define Dv   768
#define Hh   12
#define HDv  64
#define Fv   3072
#define Lv   12
#define Ov   512
#define TOK  (Bv * Sv)        // 6304
#define MPAD 6400             // TOK padded to multiple of 128
#define NPATCH 196
#define CONV_M (Bv * NPATCH)  // 6272 (multiple of 128 exactly: 49*128)

#define WQ_SZ (2304 * 768)
#define WO_SZ (768 * 768)
#define WF_SZ (3072 * 768)
#define WP_SZ (768 * 3072)
#define WTOT  (WQ_SZ + WO_SZ + WF_SZ + WP_SZ)   // 7077888

typedef __attribute__((ext_vector_type(8))) __bf16 bf16x8;
typedef __attribute__((ext_vector_type(4))) float f32x4;

__device__ __forceinline__ unsigned short f2bf(float f) {
    unsigned int u = __float_as_uint(f);
    unsigned int r = (u + 0x7fffu + ((u >> 16) & 1u)) >> 16;
    return (unsigned short)r;
}

__device__ __forceinline__ void async_ld16(const void* g, void* l) {
    __builtin_amdgcn_global_load_lds(
        (__attribute__((address_space(1))) void*)(g),
        (__attribute__((address_space(3))) void*)(l),
        16, 0, 0);
}

// ---------------------------------------------------------------------------
// block-wide (256 thread) reduction of two scalars
// ---------------------------------------------------------------------------
__device__ __forceinline__ void reduce2_256(float& s1, float& s2) {
    #pragma unroll
    for (int off = 32; off > 0; off >>= 1) {
        s1 += __shfl_down(s1, off, 64);
        s2 += __shfl_down(s2, off, 64);
    }
    __shared__ float r1[4], r2[4];
    int lane = threadIdx.x & 63, w = threadIdx.x >> 6;
    if (lane == 0) { r1[w] = s1; r2[w] = s2; }
    __syncthreads();
    s1 = r1[0] + r1[1] + r1[2] + r1[3];
    s2 = r2[0] + r2[1] + r2[2] + r2[3];
    __syncthreads();
}

// ---------------------------------------------------------------------------
// weight fp32 -> bf16 conversion
// ---------------------------------------------------------------------------
__global__ void convert_kernel(const float* __restrict__ src,
                               unsigned short* __restrict__ dst, int n4) {
    int gid = blockIdx.x * 256 + threadIdx.x;
    if (gid >= n4) return;
    int idx = gid * 4;
    float4 v = *(const float4*)(src + idx);
    ushort4 r = make_ushort4(f2bf(v.x), f2bf(v.y), f2bf(v.z), f2bf(v.w));
    *(ushort4*)(dst + idx) = r;
}

__global__ void convertw_kernel(const float* __restrict__ wq,
                                const float* __restrict__ wo,
                                const float* __restrict__ wf,
                                const float* __restrict__ wp,
                                unsigned short* __restrict__ dst) {
    int idx = (blockIdx.x * 256 + threadIdx.x) * 4;
    const float* s; int off;
    if (idx < WQ_SZ)                     { s = wq; off = idx; }
    else if (idx < WQ_SZ + WO_SZ)        { s = wo; off = idx - WQ_SZ; }
    else if (idx < WQ_SZ + WO_SZ + WF_SZ){ s = wf; off = idx - WQ_SZ - WO_SZ; }
    else                                 { s = wp; off = idx - WQ_SZ - WO_SZ - WF_SZ; }
    float4 v = *(const float4*)(s + off);
    ushort4 r = make_ushort4(f2bf(v.x), f2bf(v.y), f2bf(v.z), f2bf(v.w));
    *(ushort4*)(dst + idx) = r;
}

// ---------------------------------------------------------------------------
// im2col + normalize -> bf16 patches [6272, 768]
// ---------------------------------------------------------------------------
__global__ void im2col_kernel(const float* __restrict__ img,
                              unsigned short* __restrict__ out) {
    int idx = blockIdx.x * 256 + threadIdx.x;
    int col = idx % 768;
    int row = idx / 768;
    int b = row / NPATCH, p = row % NPATCH;
    int ph = p / 14, pw = p % 14;
    int c  = col >> 8;
    int r  = col & 255;
    int kh = r >> 4, kw = r & 15;
    int y = ph * 16 + kh, x = pw * 16 + kw;
    const float mean[3] = {0.48145466f, 0.4578275f, 0.40821073f};
    const float stdv[3] = {0.26862954f, 0.26130258f, 0.27577711f};
    float v = img[((size_t)(b * 3 + c) * 224 + y) * 224 + x];
    out[idx] = f2bf((v - mean[c]) / stdv[c]);
}

// ---------------------------------------------------------------------------
// MFMA bf16 GEMM: C[m,n] = sum_k A[m,k]*W[n,k] (+bias) (+res fp32) (QuickGELU)
// 128x128 tile, BK=32, 256 threads (4 waves, each 64x64 quadrant of the tile).
// A [Mpad,K] bf16, W [N,K] bf16. N%128==0, K%32==0. Store guarded by m<M.
// ODT: 0 = fp32 out, 1 = bf16 out.
// ---------------------------------------------------------------------------
template<int ODT, int ACT>
__global__ __launch_bounds__(256) void gemm_mfma(
        const unsigned short* __restrict__ A, const unsigned short* __restrict__ W,
        const float* __restrict__ bias, const float* __restrict__ res,
        void* __restrict__ Cv, int M, int N, int K)
{
    __shared__ unsigned short As[128 * 32];
    __shared__ unsigned short Ws[128 * 32];
    const int tid = threadIdx.x;
    const int w = tid >> 6, l = tid & 63;
    const int m0 = blockIdx.y << 7, n0 = blockIdx.x << 7;

    // staging: wave w covers rows w*32 .. w*32+31 of each 128x32 tile,
    // two global_load_lds(16B) per wave per tile.
    const int srow = w * 32 + (l >> 2);
    const int scol = (l & 3) * 8;                 // elements (16B chunks)
    const unsigned short* ag0 = A + (size_t)(m0 + srow) * K + scol;
    const unsigned short* ag1 = ag0 + (size_t)16 * K;
    const unsigned short* wg0 = W + (size_t)(n0 + srow) * K + scol;
    const unsigned short* wg1 = wg0 + (size_t)16 * K;
    unsigned short* al0 = As + w * 1024;
    unsigned short* al1 = As + w * 1024 + 512;
    unsigned short* wl0 = Ws + w * 1024;
    unsigned short* wl1 = Ws + w * 1024 + 512;

    const int wm = w >> 1, wn = w & 1;
    const int fr = l & 15, fq = l >> 4;
    const unsigned short* afp[4];
    const unsigned short* wfp[4];
    #pragma unroll
    for (int i = 0; i < 4; i++) {
        afp[i] = As + (wm * 64 + i * 16 + fr) * 32 + fq * 8;
        wfp[i] = Ws + (wn * 64 + i * 16 + fr) * 32 + fq * 8;
    }

    f32x4 acc[4][4] = {};

    const int nk = K >> 5;
    for (int kk = 0; kk < nk; kk++) {
        const int ko = kk << 5;
        __syncthreads();
        async_ld16(ag0 + ko, al0);
        async_ld16(ag1 + ko, al1);
        async_ld16(wg0 + ko, wl0);
        async_ld16(wg1 + ko, wl1);
        __syncthreads();
        bf16x8 af[4], wf[4];
        #pragma unroll
        for (int i = 0; i < 4; i++) {
            af[i] = *(const bf16x8*)afp[i];
            wf[i] = *(const bf16x8*)wfp[i];
        }
        #pragma unroll
        for (int i = 0; i < 4; i++) {
            #pragma unroll
            for (int j = 0; j < 4; j++) {
                acc[i][j] = __builtin_amdgcn_mfma_f32_16x16x32_bf16(
                    af[i], wf[j], acc[i][j], 0, 0, 0);
            }
        }
    }

    float bn[4];
    #pragma unroll
    for (int j = 0; j < 4; j++)
        bn[j] = bias ? bias[n0 + wn * 64 + j * 16 + fr] : 0.f;

    #pragma unroll
    for (int i = 0; i < 4; i++) {
        #pragma unroll
        for (int r = 0; r < 4; r++) {
            int m = m0 + wm * 64 + i * 16 + fq * 4 + r;
            if (m < M) {
                size_t rowb = (size_t)m * N;
                #pragma unroll
                for (int j = 0; j < 4; j++) {
                    int n = n0 + wn * 64 + j * 16 + fr;
                    float v = acc[i][j][r] + bn[j];
                    if (res) v += res[rowb + n];
                    if (ACT) v = v / (1.f + __expf(-1.702f * v));
                    if (ODT == 0) ((float*)Cv)[rowb + n] = v;
                    else ((unsigned short*)Cv)[rowb + n] = f2bf(v);
                }
            }
        }
    }
}

// ---------------------------------------------------------------------------
// LayerNorm fp32 in -> bf16 out. One block per token.
// ---------------------------------------------------------------------------
__global__ void ln_kernel(const float* __restrict__ in, unsigned short* __restrict__ out,
                          const float* __restrict__ s, const float* __restrict__ b) {
    int t = blockIdx.x;
    const float* row = in + (size_t)t * Dv;
    int tid = threadIdx.x;
    float v[3], s1 = 0.f, s2 = 0.f;
    #pragma unroll
    for (int i = 0; i < 3; i++) {
        v[i] = row[tid + 256 * i];
        s1 += v[i]; s2 += v[i] * v[i];
    }
    reduce2_256(s1, s2);
    float mean = s1 * (1.0f / Dv);
    float var  = s2 * (1.0f / Dv) - mean * mean;
    float rstd = rsqrtf(var + 1e-5f);
    unsigned short* orow = out + (size_t)t * Dv;
    #pragma unroll
    for (int i = 0; i < 3; i++) {
        int d = tid + 256 * i;
        orow[d] = f2bf((v[i] - mean) * rstd * s[d] + b[d]);
    }
}

// ---------------------------------------------------------------------------
// embed (cls/patch + pos) + ln_pre -> x fp32. One block per token.
// ---------------------------------------------------------------------------
__global__ void embed_ln_kernel(const float* __restrict__ conv_out,
                                const float* __restrict__ cls,
                                const float* __restrict__ pos,
                                const float* __restrict__ s,
                                const float* __restrict__ b,
                                float* __restrict__ x) {
    int t = blockIdx.x;
    int bb = t / Sv, si = t % Sv;
    int tid = threadIdx.x;
    float v[3], s1 = 0.f, s2 = 0.f;
    #pragma unroll
    for (int i = 0; i < 3; i++) {
        int d = tid + 256 * i;
        float e = (si == 0) ? cls[d]
                            : conv_out[((size_t)bb * NPATCH + (si - 1)) * Dv + d];
        v[i] = e + pos[(size_t)si * Dv + d];
        s1 += v[i]; s2 += v[i] * v[i];
    }
    reduce2_256(s1, s2);
    float mean = s1 * (1.0f / Dv);
    float var  = s2 * (1.0f / Dv) - mean * mean;
    float rstd = rsqrtf(var + 1e-5f);
    float* orow = x + (size_t)t * Dv;
    #pragma unroll
    for (int i = 0; i < 3; i++) {
        int d = tid + 256 * i;
        orow[d] = (v[i] - mean) * rstd * s[d] + b[d];
    }
}

// ---------------------------------------------------------------------------
// Attention v2: one 256-thread block per (h, b). K and V^T staged in LDS as
// bf16; each wave handles q rows r = w, w+4, ... with q broadcast in regs.
// qkv bf16 [TOK, 2304] packed q|k|v each [12, 64]. Out bf16 [TOK, 768].
// ---------------------------------------------------------------------------
__global__ __launch_bounds__(256) void attn2_kernel(
        const unsigned short* __restrict__ qkv, unsigned short* __restrict__ o) {
    int h = blockIdx.x, b = blockIdx.y;
    __shared__ unsigned int   ks[197][33];     // K rows, 32 uints (=64 bf16) + pad
    __shared__ unsigned short vt[64][202];     // V transposed [d][j], pad to 202
    __shared__ float          ps[4][208];      // per-wave softmax probs

    const unsigned int* q32 = (const unsigned int*)qkv;   // row stride 1152 uints
    const int tid = threadIdx.x;
    const size_t base = (size_t)b * Sv;

    for (int i = tid; i < 197 * 32; i += 256) {
        int j = i >> 5, u = i & 31;
        ks[j][u] = q32[(base + j) * 1152 + 384 + h * 32 + u];
    }
    for (int i = tid; i < 197 * 32; i += 256) {
        int j = i >> 5, u = i & 31;
        unsigned int v = q32[(base + j) * 1152 + 768 + h * 32 + u];
        vt[u * 2][j]     = (unsigned short)(v & 0xffffu);
        vt[u * 2 + 1][j] = (unsigned short)(v >> 16);
    }
    if (tid < 64) vt[tid][197] = 0;   // read as the 198th element of V^T rows
    __syncthreads();

    const int w = tid >> 6, l = tid & 63;
    for (int r = w; r < Sv; r += 4) {
        const unsigned int* qr = q32 + (base + r) * 1152 + h * 32;
        float qv[64];
        #pragma unroll
        for (int u = 0; u < 32; u++) {
            unsigned int qu = qr[u];
            qv[2 * u]     = __uint_as_float(qu << 16);
            qv[2 * u + 1] = __uint_as_float(qu & 0xffff0000u);
        }
        float sc[4];
        float smax = -1e30f;
        #pragma unroll
        for (int jj = 0; jj < 4; jj++) {
            int j = l + jj * 64;
            float acc = -1e30f;
            if (j < Sv) {
                acc = 0.f;
                #pragma unroll
                for (int u = 0; u < 32; u++) {
                    unsigned int ku = ks[j][u];
                    acc += qv[2 * u]     * __uint_as_float(ku << 16);
                    acc += qv[2 * u + 1] * __uint_as_float(ku & 0xffff0000u);
                }
                acc *= 0.125f;
            }
            sc[jj] = acc;
            smax = fmaxf(smax, acc);
        }
        #pragma unroll
        for (int off = 32; off > 0; off >>= 1)
            smax = fmaxf(smax, __shfl_xor(smax, off, 64));

        float ssum = 0.f;
        #pragma unroll
        for (int jj = 0; jj < 4; jj++) {
            int j = l + jj * 64;
            if (j < Sv) {
                float p = __expf(sc[jj] - smax);
                ps[w][j] = p;
                ssum += p;
            } else if (j < 208) {
                ps[w][j] = 0.f;
            }
        }
        #pragma unroll
        for (int off = 32; off > 0; off >>= 1)
            ssum += __shfl_xor(ssum, off, 64);

        float acc = 0.f;
        const unsigned int* vr = (const unsigned int*)&vt[l][0];
        for (int jj = 0; jj < 99; jj++) {
            float2 pp = *(const float2*)&ps[w][2 * jj];
            unsigned int vv = vr[jj];
            acc += pp.x * __uint_as_float(vv << 16);
            acc += pp.y * __uint_as_float(vv & 0xffff0000u);
        }
        o[(base + r) * Dv + h * 64 + l] = f2bf(acc / ssum);
    }
}

// ---------------------------------------------------------------------------
// Head: ln_post on cls token + @ vis_proj [768,512] fp32. One block per batch.
// ---------------------------------------------------------------------------
__global__ void head_kernel(const float* __restrict__ x,
                            const float* __restrict__ s, const float* __restrict__ b,
                            const float* __restrict__ vp, float* __restrict__ out) {
    int bb = blockIdx.x, tid = threadIdx.x;
    __shared__ float xn[Dv];
    const float* row = x + (size_t)(bb * Sv) * Dv;
    float v[3], s1 = 0.f, s2 = 0.f;
    #pragma unroll
    for (int i = 0; i < 3; i++) {
        v[i] = row[tid + 256 * i];
        s1 += v[i]; s2 += v[i] * v[i];
    }
    reduce2_256(s1, s2);
    float mean = s1 * (1.0f / Dv);
    float var  = s2 * (1.0f / Dv) - mean * mean;
    float rstd = rsqrtf(var + 1e-5f);
    #pragma unroll
    for (int i = 0; i < 3; i++) {
        int d = tid + 256 * i;
        xn[d] = (v[i] - mean) * rstd * s[d] + b[d];
    }
    __syncthreads();
    float acc0 = 0.f, acc1 = 0.f;
    for (int d = 0; d < Dv; d++) {
        float xv = xn[d];
        acc0 += xv * vp[(size_t)d * Ov + tid];
        acc1 += xv * vp[(size_t)d * Ov + tid + 256];
    }
    out[(size_t)bb * Ov + tid]       = acc0;
    out[(size_t)bb * Ov + tid + 256] = acc1;
}

// ---------------------------------------------------------------------------
extern "C" void kernel_launch(void* const* d_in, const int* in_sizes, int n_in,
                              void* d_out, int out_size, void* d_ws, size_t ws_size,
                              hipStream_t stream) {
    const float* images   = (const float*)d_in[0];
    const float* conv_w   = (const float*)d_in[1];
    const float* cls_emb  = (const float*)d_in[2];
    const float* pos_emb  = (const float*)d_in[3];
    const float* lnpre_s  = (const float*)d_in[4];
    const float* lnpre_b  = (const float*)d_in[5];
    const float* ln1_s    = (const float*)d_in[6];
    const float* ln1_b    = (const float*)d_in[7];
    const float* qkv_w    = (const float*)d_in[8];
    const float* qkv_b    = (const float*)d_in[9];
    const float* out_w    = (const float*)d_in[10];
    const float* out_b    = (const float*)d_in[11];
    const float* ln2_s    = (const float*)d_in[12];
    const float* ln2_b    = (const float*)d_in[13];
    const float* fc_w     = (const float*)d_in[14];
    const float* fc_b     = (const float*)d_in[15];
    const float* proj_w   = (const float*)d_in[16];
    const float* proj_b   = (const float*)d_in[17];
    const float* lnpost_s = (const float*)d_in[18];
    const float* lnpost_b = (const float*)d_in[19];
    const float* vis_proj = (const float*)d_in[20];
    float* out = (float*)d_out;

    char* p = (char*)d_ws;
    float* x              = (float*)p;          p += (size_t)TOK * Dv * 4;       // 19.4 MB
    unsigned short* abuf  = (unsigned short*)p; p += (size_t)MPAD * Dv * 2;      //  9.8 MB
    unsigned short* qkvb  = (unsigned short*)p; p += (size_t)MPAD * 2304 * 2;    // 29.5 MB
    unsigned short* hbuf  = (unsigned short*)p; p += (size_t)MPAD * Fv * 2;      // 39.3 MB
    unsigned short* wbuf  = (unsigned short*)p; p += (size_t)WTOT * 2;           // 14.2 MB
    unsigned short* cwb   = (unsigned short*)p; p += (size_t)WO_SZ * 2;          //  1.2 MB
    // aliases (pre-loop only):
    unsigned short* im2c  = qkvb;               // [6272,768] bf16
    float* convo          = (float*)hbuf;       // [6272,768] fp32

    // patch embedding
    convert_kernel<<<WO_SZ / 4 / 256, 256, 0, stream>>>(conv_w, cwb, WO_SZ / 4);
    im2col_kernel<<<(CONV_M * Dv) / 256, 256, 0, stream>>>(images, im2c);
    gemm_mfma<0, 0><<<dim3(Dv / 128, CONV_M / 128), 256, 0, stream>>>(
        im2c, cwb, nullptr, nullptr, convo, CONV_M, Dv, Dv);
    embed_ln_kernel<<<TOK, 256, 0, stream>>>(convo, cls_emb, pos_emb,
                                             lnpre_s, lnpre_b, x);

    unsigned short* wq = wbuf;
    unsigned short* wo = wbuf + WQ_SZ;
    unsigned short* wf = wbuf + WQ_SZ + WO_SZ;
    unsigned short* wp = wbuf + WQ_SZ + WO_SZ + WF_SZ;
    const int GM = MPAD / 128;   // 50

    for (int l = 0; l < Lv; l++) {
        convertw_kernel<<<WTOT / 4 / 256, 256, 0, stream>>>(
            qkv_w + (size_t)l * WQ_SZ, out_w + (size_t)l * WO_SZ,
            fc_w + (size_t)l * WF_SZ, proj_w + (size_t)l * WP_SZ, wbuf);
        ln_kernel<<<TOK, 256, 0, stream>>>(x, abuf, ln1_s + l * Dv, ln1_b + l * Dv);
        gemm_mfma<1, 0><<<dim3(2304 / 128, GM), 256, 0, stream>>>(
            abuf, wq, qkv_b + (size_t)l * 2304, nullptr, qkvb, TOK, 2304, Dv);
        attn2_kernel<<<dim3(Hh, Bv), 256, 0, stream>>>(qkvb, abuf);
        gemm_mfma<0, 0><<<dim3(Dv / 128, GM), 256, 0, stream>>>(
            abuf, wo, out_b + (size_t)l * Dv, x, x, TOK, Dv, Dv);
        ln_kernel<<<TOK, 256, 0, stream>>>(x, abuf, ln2_s + l * Dv, ln2_b + l * Dv);
        gemm_mfma<1, 1><<<dim3(Fv / 128, GM), 256, 0, stream>>>(
            abuf, wf, fc_b + (size_t)l * Fv, nullptr, hbuf, TOK, Fv, Dv);
        gemm_mfma<0, 0><<<dim3(Dv / 128, GM), 256, 0, stream>>>(
            hbuf, wp, proj_b + (size_t)l * Dv, x, x, TOK, Dv, Fv);
    }

    head_kernel<<<Bv, 256, 0, stream>>>(x, lnpost_s, lnpost_b, vis_proj, out);
}

// Round 3
// 8345.194 us; speedup vs baseline: 3.5952x; 1.1243x over previous
//
#include <hip/hip_runtime.h>
#include <cstddef>

#define Bv   32
#define Sv   197
#define Dv   768
#define Hh   12
#define HDv  64
#define Fv   3072
#define Lv   12
#define Ov   512
#define TOK  (Bv * Sv)        // 6304
#define MPAD 6400             // TOK padded to multiple of 128
#define NPATCH 196
#define CONV_M (Bv * NPATCH)  // 6272 (multiple of 128 exactly: 49*128)

#define WQ_SZ (2304 * 768)
#define WO_SZ (768 * 768)
#define WF_SZ (3072 * 768)
#define WP_SZ (768 * 3072)
#define WTOT  (WQ_SZ + WO_SZ + WF_SZ + WP_SZ)   // 7077888

typedef __attribute__((ext_vector_type(8))) __bf16 bf16x8;
typedef __attribute__((ext_vector_type(4))) float f32x4;

__device__ __forceinline__ unsigned short f2bf(float f) {
    unsigned int u = __float_as_uint(f);
    unsigned int r = (u + 0x7fffu + ((u >> 16) & 1u)) >> 16;
    return (unsigned short)r;
}
__device__ __forceinline__ float bflo(unsigned int u) { return __uint_as_float(u << 16); }
__device__ __forceinline__ float bfhi(unsigned int u) { return __uint_as_float(u & 0xffff0000u); }

__device__ __forceinline__ void async_ld16(const void* g, void* l) {
    __builtin_amdgcn_global_load_lds(
        (__attribute__((address_space(1))) void*)(g),
        (__attribute__((address_space(3))) void*)(l),
        16, 0, 0);
}

// ---------------------------------------------------------------------------
// block-wide (256 thread) reduction of two scalars
// ---------------------------------------------------------------------------
__device__ __forceinline__ void reduce2_256(float& s1, float& s2) {
    #pragma unroll
    for (int off = 32; off > 0; off >>= 1) {
        s1 += __shfl_down(s1, off, 64);
        s2 += __shfl_down(s2, off, 64);
    }
    __shared__ float r1[4], r2[4];
    int lane = threadIdx.x & 63, w = threadIdx.x >> 6;
    if (lane == 0) { r1[w] = s1; r2[w] = s2; }
    __syncthreads();
    s1 = r1[0] + r1[1] + r1[2] + r1[3];
    s2 = r2[0] + r2[1] + r2[2] + r2[3];
    __syncthreads();
}

// ---------------------------------------------------------------------------
// weight fp32 -> bf16 conversion
// ---------------------------------------------------------------------------
__global__ void convert_kernel(const float* __restrict__ src,
                               unsigned short* __restrict__ dst, int n4) {
    int gid = blockIdx.x * 256 + threadIdx.x;
    if (gid >= n4) return;
    int idx = gid * 4;
    float4 v = *(const float4*)(src + idx);
    ushort4 r = make_ushort4(f2bf(v.x), f2bf(v.y), f2bf(v.z), f2bf(v.w));
    *(ushort4*)(dst + idx) = r;
}

__global__ void convertw_kernel(const float* __restrict__ wq,
                                const float* __restrict__ wo,
                                const float* __restrict__ wf,
                                const float* __restrict__ wp,
                                unsigned short* __restrict__ dst) {
    int idx = (blockIdx.x * 256 + threadIdx.x) * 4;
    const float* s; int off;
    if (idx < WQ_SZ)                     { s = wq; off = idx; }
    else if (idx < WQ_SZ + WO_SZ)        { s = wo; off = idx - WQ_SZ; }
    else if (idx < WQ_SZ + WO_SZ + WF_SZ){ s = wf; off = idx - WQ_SZ - WO_SZ; }
    else                                 { s = wp; off = idx - WQ_SZ - WO_SZ - WF_SZ; }
    float4 v = *(const float4*)(s + off);
    ushort4 r = make_ushort4(f2bf(v.x), f2bf(v.y), f2bf(v.z), f2bf(v.w));
    *(ushort4*)(dst + idx) = r;
}

// ---------------------------------------------------------------------------
// im2col + normalize -> bf16 patches [6272, 768]
// ---------------------------------------------------------------------------
__global__ void im2col_kernel(const float* __restrict__ img,
                              unsigned short* __restrict__ out) {
    int idx = blockIdx.x * 256 + threadIdx.x;
    int col = idx % 768;
    int row = idx / 768;
    int b = row / NPATCH, p = row % NPATCH;
    int ph = p / 14, pw = p % 14;
    int c  = col >> 8;
    int r  = col & 255;
    int kh = r >> 4, kw = r & 15;
    int y = ph * 16 + kh, x = pw * 16 + kw;
    const float mean[3] = {0.48145466f, 0.4578275f, 0.40821073f};
    const float stdv[3] = {0.26862954f, 0.26130258f, 0.27577711f};
    float v = img[((size_t)(b * 3 + c) * 224 + y) * 224 + x];
    out[idx] = f2bf((v - mean[c]) / stdv[c]);
}

// ---------------------------------------------------------------------------
// MFMA bf16 GEMM: C[m,n] = sum_k A[m,k]*W[n,k] (+bias) (+res fp32) (QuickGELU)
// 128x128 tile, BK=32, 256 threads (4 waves, each 64x64 quadrant).
// ---------------------------------------------------------------------------
template<int ODT, int ACT>
__global__ __launch_bounds__(256) void gemm_mfma(
        const unsigned short* __restrict__ A, const unsigned short* __restrict__ W,
        const float* __restrict__ bias, const float* __restrict__ res,
        void* __restrict__ Cv, int M, int N, int K)
{
    __shared__ unsigned short As[128 * 32];
    __shared__ unsigned short Ws[128 * 32];
    const int tid = threadIdx.x;
    const int w = tid >> 6, l = tid & 63;
    const int m0 = blockIdx.y << 7, n0 = blockIdx.x << 7;

    const int srow = w * 32 + (l >> 2);
    const int scol = (l & 3) * 8;
    const unsigned short* ag0 = A + (size_t)(m0 + srow) * K + scol;
    const unsigned short* ag1 = ag0 + (size_t)16 * K;
    const unsigned short* wg0 = W + (size_t)(n0 + srow) * K + scol;
    const unsigned short* wg1 = wg0 + (size_t)16 * K;
    unsigned short* al0 = As + w * 1024;
    unsigned short* al1 = As + w * 1024 + 512;
    unsigned short* wl0 = Ws + w * 1024;
    unsigned short* wl1 = Ws + w * 1024 + 512;

    const int wm = w >> 1, wn = w & 1;
    const int fr = l & 15, fq = l >> 4;
    const unsigned short* afp[4];
    const unsigned short* wfp[4];
    #pragma unroll
    for (int i = 0; i < 4; i++) {
        afp[i] = As + (wm * 64 + i * 16 + fr) * 32 + fq * 8;
        wfp[i] = Ws + (wn * 64 + i * 16 + fr) * 32 + fq * 8;
    }

    f32x4 acc[4][4] = {};

    const int nk = K >> 5;
    for (int kk = 0; kk < nk; kk++) {
        const int ko = kk << 5;
        __syncthreads();
        async_ld16(ag0 + ko, al0);
        async_ld16(ag1 + ko, al1);
        async_ld16(wg0 + ko, wl0);
        async_ld16(wg1 + ko, wl1);
        __syncthreads();
        bf16x8 af[4], wf[4];
        #pragma unroll
        for (int i = 0; i < 4; i++) {
            af[i] = *(const bf16x8*)afp[i];
            wf[i] = *(const bf16x8*)wfp[i];
        }
        #pragma unroll
        for (int i = 0; i < 4; i++) {
            #pragma unroll
            for (int j = 0; j < 4; j++) {
                acc[i][j] = __builtin_amdgcn_mfma_f32_16x16x32_bf16(
                    af[i], wf[j], acc[i][j], 0, 0, 0);
            }
        }
    }

    float bn[4];
    #pragma unroll
    for (int j = 0; j < 4; j++)
        bn[j] = bias ? bias[n0 + wn * 64 + j * 16 + fr] : 0.f;

    #pragma unroll
    for (int i = 0; i < 4; i++) {
        #pragma unroll
        for (int r = 0; r < 4; r++) {
            int m = m0 + wm * 64 + i * 16 + fq * 4 + r;
            if (m < M) {
                size_t rowb = (size_t)m * N;
                #pragma unroll
                for (int j = 0; j < 4; j++) {
                    int n = n0 + wn * 64 + j * 16 + fr;
                    float v = acc[i][j][r] + bn[j];
                    if (res) v += res[rowb + n];
                    if (ACT) v = v / (1.f + __expf(-1.702f * v));
                    if (ODT == 0) ((float*)Cv)[rowb + n] = v;
                    else ((unsigned short*)Cv)[rowb + n] = f2bf(v);
                }
            }
        }
    }
}

// ---------------------------------------------------------------------------
// LayerNorm fp32 in -> bf16 out. One block per token.
// ---------------------------------------------------------------------------
__global__ void ln_kernel(const float* __restrict__ in, unsigned short* __restrict__ out,
                          const float* __restrict__ s, const float* __restrict__ b) {
    int t = blockIdx.x;
    const float* row = in + (size_t)t * Dv;
    int tid = threadIdx.x;
    float v[3], s1 = 0.f, s2 = 0.f;
    #pragma unroll
    for (int i = 0; i < 3; i++) {
        v[i] = row[tid + 256 * i];
        s1 += v[i]; s2 += v[i] * v[i];
    }
    reduce2_256(s1, s2);
    float mean = s1 * (1.0f / Dv);
    float var  = s2 * (1.0f / Dv) - mean * mean;
    float rstd = rsqrtf(var + 1e-5f);
    unsigned short* orow = out + (size_t)t * Dv;
    #pragma unroll
    for (int i = 0; i < 3; i++) {
        int d = tid + 256 * i;
        orow[d] = f2bf((v[i] - mean) * rstd * s[d] + b[d]);
    }
}

// ---------------------------------------------------------------------------
// embed (cls/patch + pos) + ln_pre -> x fp32. One block per token.
// ---------------------------------------------------------------------------
__global__ void embed_ln_kernel(const float* __restrict__ conv_out,
                                const float* __restrict__ cls,
                                const float* __restrict__ pos,
                                const float* __restrict__ s,
                                const float* __restrict__ b,
                                float* __restrict__ x) {
    int t = blockIdx.x;
    int bb = t / Sv, si = t % Sv;
    int tid = threadIdx.x;
    float v[3], s1 = 0.f, s2 = 0.f;
    #pragma unroll
    for (int i = 0; i < 3; i++) {
        int d = tid + 256 * i;
        float e = (si == 0) ? cls[d]
                            : conv_out[((size_t)bb * NPATCH + (si - 1)) * Dv + d];
        v[i] = e + pos[(size_t)si * Dv + d];
        s1 += v[i]; s2 += v[i] * v[i];
    }
    reduce2_256(s1, s2);
    float mean = s1 * (1.0f / Dv);
    float var  = s2 * (1.0f / Dv) - mean * mean;
    float rstd = rsqrtf(var + 1e-5f);
    float* orow = x + (size_t)t * Dv;
    #pragma unroll
    for (int i = 0; i < 3; i++) {
        int d = tid + 256 * i;
        orow[d] = (v[i] - mean) * rstd * s[d] + b[d];
    }
}

// ---------------------------------------------------------------------------
// Attention v3: grid (7, H, B); block = 256 thr = 4 waves; block covers 32
// q-rows (qg*32..+31), wave w rows [qg*32+w*8, +8) in 2 chunks of 4.
// K staged in LDS (stride-33 uints, conflict-free). V read from global
// (one 128B line per wave-load), amortized over 4 q-rows per pass.
// qkv bf16 [TOK, 2304] packed q|k|v each [12, 64]. Out bf16 [TOK, 768].
// ---------------------------------------------------------------------------
__global__ __launch_bounds__(256) void attn3_kernel(
        const unsigned short* __restrict__ qkv, unsigned short* __restrict__ o) {
    int qg = blockIdx.x, h = blockIdx.y, b = blockIdx.z;
    __shared__ unsigned int ks[197 * 33];   // 26.0 KB
    __shared__ float ps[4][4][200];         // 12.8 KB

    const unsigned int* q32 = (const unsigned int*)qkv;   // row stride 1152 uints
    const int tid = threadIdx.x;
    const size_t base = (size_t)b * Sv;

    for (int i = tid; i < 197 * 32; i += 256) {
        int j = i >> 5, u = i & 31;
        ks[j * 33 + u] = q32[(base + j) * 1152 + 384 + h * 32 + u];
    }
    __syncthreads();

    const int w = tid >> 6, l = tid & 63;
    const int rbase = qg * 32 + w * 8;
    const unsigned short* vg = qkv + base * 2304 + 1536 + h * 64 + l;

    #pragma unroll
    for (int c = 0; c < 2; c++) {
        const int r0 = rbase + c * 4;
        float ssum[4];
        int nr = 0;
        for (int i = 0; i < 4; i++) {
            int r = r0 + i;
            if (r >= Sv) break;            // wave-uniform
            nr = i + 1;
            // broadcast q row into registers
            float qv[64];
            const uint4* qr = (const uint4*)(q32 + (base + r) * 1152 + h * 32);
            #pragma unroll
            for (int u4 = 0; u4 < 8; u4++) {
                uint4 q4 = qr[u4];
                qv[u4 * 8 + 0] = bflo(q4.x); qv[u4 * 8 + 1] = bfhi(q4.x);
                qv[u4 * 8 + 2] = bflo(q4.y); qv[u4 * 8 + 3] = bfhi(q4.y);
                qv[u4 * 8 + 4] = bflo(q4.z); qv[u4 * 8 + 5] = bfhi(q4.z);
                qv[u4 * 8 + 6] = bflo(q4.w); qv[u4 * 8 + 7] = bfhi(q4.w);
            }
            float sc[4];
            float smax = -1e30f;
            #pragma unroll
            for (int jj = 0; jj < 4; jj++) {
                int j = l + jj * 64;
                float acc = -1e30f;
                if (j < Sv) {
                    acc = 0.f;
                    #pragma unroll
                    for (int u = 0; u < 32; u++) {
                        unsigned int ku = ks[j * 33 + u];
                        acc += qv[2 * u]     * bflo(ku);
                        acc += qv[2 * u + 1] * bfhi(ku);
                    }
                    acc *= 0.125f;
                }
                sc[jj] = acc;
                smax = fmaxf(smax, acc);
            }
            #pragma unroll
            for (int off = 32; off > 0; off >>= 1)
                smax = fmaxf(smax, __shfl_xor(smax, off, 64));
            float s = 0.f;
            #pragma unroll
            for (int jj = 0; jj < 4; jj++) {
                int j = l + jj * 64;
                if (j < Sv) {
                    float p = __expf(sc[jj] - smax);
                    ps[w][i][j] = p;
                    s += p;
                }
            }
            #pragma unroll
            for (int off = 32; off > 0; off >>= 1)
                s += __shfl_xor(s, off, 64);
            ssum[i] = s;
        }
        if (nr > 0) {
            float acc0 = 0.f, acc1 = 0.f, acc2 = 0.f, acc3 = 0.f;
            #pragma unroll 4
            for (int j = 0; j < Sv; j++) {
                float v = bflo((unsigned int)vg[(size_t)j * 2304] << 16 >> 16);
                // (single ushort load; bflo(x<<16>>16) == convert low bf16)
                unsigned int uv = (unsigned int)vg[(size_t)j * 2304];
                v = __uint_as_float(uv << 16);
                acc0 += ps[w][0][j] * v;
                acc1 += ps[w][1][j] * v;
                acc2 += ps[w][2][j] * v;
                acc3 += ps[w][3][j] * v;
            }
            float acc[4] = {acc0, acc1, acc2, acc3};
            for (int i = 0; i < nr; i++)
                o[(base + r0 + i) * Dv + h * 64 + l] = f2bf(acc[i] / ssum[i]);
        }
    }
}

// ---------------------------------------------------------------------------
// Head: ln_post on cls token + @ vis_proj [768,512] fp32. One block per batch.
// ---------------------------------------------------------------------------
__global__ void head_kernel(const float* __restrict__ x,
                            const float* __restrict__ s, const float* __restrict__ b,
                            const float* __restrict__ vp, float* __restrict__ out) {
    int bb = blockIdx.x, tid = threadIdx.x;
    __shared__ float xn[Dv];
    const float* row = x + (size_t)(bb * Sv) * Dv;
    float v[3], s1 = 0.f, s2 = 0.f;
    #pragma unroll
    for (int i = 0; i < 3; i++) {
        v[i] = row[tid + 256 * i];
        s1 += v[i]; s2 += v[i] * v[i];
    }
    reduce2_256(s1, s2);
    float mean = s1 * (1.0f / Dv);
    float var  = s2 * (1.0f / Dv) - mean * mean;
    float rstd = rsqrtf(var + 1e-5f);
    #pragma unroll
    for (int i = 0; i < 3; i++) {
        int d = tid + 256 * i;
        xn[d] = (v[i] - mean) * rstd * s[d] + b[d];
    }
    __syncthreads();
    float acc0 = 0.f, acc1 = 0.f;
    for (int d = 0; d < Dv; d++) {
        float xv = xn[d];
        acc0 += xv * vp[(size_t)d * Ov + tid];
        acc1 += xv * vp[(size_t)d * Ov + tid + 256];
    }
    out[(size_t)bb * Ov + tid]       = acc0;
    out[(size_t)bb * Ov + tid + 256] = acc1;
}

// ---------------------------------------------------------------------------
extern "C" void kernel_launch(void* const* d_in, const int* in_sizes, int n_in,
                              void* d_out, int out_size, void* d_ws, size_t ws_size,
                              hipStream_t stream) {
    const float* images   = (const float*)d_in[0];
    const float* conv_w   = (const float*)d_in[1];
    const float* cls_emb  = (const float*)d_in[2];
    const float* pos_emb  = (const float*)d_in[3];
    const float* lnpre_s  = (const float*)d_in[4];
    const float* lnpre_b  = (const float*)d_in[5];
    const float* ln1_s    = (const float*)d_in[6];
    const float* ln1_b    = (const float*)d_in[7];
    const float* qkv_w    = (const float*)d_in[8];
    const float* qkv_b    = (const float*)d_in[9];
    const float* out_w    = (const float*)d_in[10];
    const float* out_b    = (const float*)d_in[11];
    const float* ln2_s    = (const float*)d_in[12];
    const float* ln2_b    = (const float*)d_in[13];
    const float* fc_w     = (const float*)d_in[14];
    const float* fc_b     = (const float*)d_in[15];
    const float* proj_w   = (const float*)d_in[16];
    const float* proj_b   = (const float*)d_in[17];
    const float* lnpost_s = (const float*)d_in[18];
    const float* lnpost_b = (const float*)d_in[19];
    const float* vis_proj = (const float*)d_in[20];
    float* out = (float*)d_out;

    char* p = (char*)d_ws;
    float* x              = (float*)p;          p += (size_t)TOK * Dv * 4;       // 19.4 MB
    unsigned short* abuf  = (unsigned short*)p; p += (size_t)MPAD * Dv * 2;      //  9.8 MB
    unsigned short* qkvb  = (unsigned short*)p; p += (size_t)MPAD * 2304 * 2;    // 29.5 MB
    unsigned short* hbuf  = (unsigned short*)p; p += (size_t)MPAD * Fv * 2;      // 39.3 MB
    unsigned short* wbuf  = (unsigned short*)p; p += (size_t)WTOT * 2;           // 14.2 MB
    unsigned short* cwb   = (unsigned short*)p; p += (size_t)WO_SZ * 2;          //  1.2 MB
    // aliases (pre-loop only):
    unsigned short* im2c  = qkvb;               // [6272,768] bf16
    float* convo          = (float*)hbuf;       // [6272,768] fp32

    // patch embedding
    convert_kernel<<<WO_SZ / 4 / 256, 256, 0, stream>>>(conv_w, cwb, WO_SZ / 4);
    im2col_kernel<<<(CONV_M * Dv) / 256, 256, 0, stream>>>(images, im2c);
    gemm_mfma<0, 0><<<dim3(Dv / 128, CONV_M / 128), 256, 0, stream>>>(
        im2c, cwb, nullptr, nullptr, convo, CONV_M, Dv, Dv);
    embed_ln_kernel<<<TOK, 256, 0, stream>>>(convo, cls_emb, pos_emb,
                                             lnpre_s, lnpre_b, x);

    unsigned short* wq = wbuf;
    unsigned short* wo = wbuf + WQ_SZ;
    unsigned short* wf = wbuf + WQ_SZ + WO_SZ;
    unsigned short* wp = wbuf + WQ_SZ + WO_SZ + WF_SZ;
    const int GM = MPAD / 128;   // 50

    for (int l = 0; l < Lv; l++) {
        convertw_kernel<<<WTOT / 4 / 256, 256, 0, stream>>>(
            qkv_w + (size_t)l * WQ_SZ, out_w + (size_t)l * WO_SZ,
            fc_w + (size_t)l * WF_SZ, proj_w + (size_t)l * WP_SZ, wbuf);
        ln_kernel<<<TOK, 256, 0, stream>>>(x, abuf, ln1_s + l * Dv, ln1_b + l * Dv);
        gemm_mfma<1, 0><<<dim3(2304 / 128, GM), 256, 0, stream>>>(
            abuf, wq, qkv_b + (size_t)l * 2304, nullptr, qkvb, TOK, 2304, Dv);
        attn3_kernel<<<dim3(7, Hh, Bv), 256, 0, stream>>>(qkvb, abuf);
        gemm_mfma<0, 0><<<dim3(Dv / 128, GM), 256, 0, stream>>>(
            abuf, wo, out_b + (size_t)l * Dv, x, x, TOK, Dv, Dv);
        ln_kernel<<<TOK, 256, 0, stream>>>(x, abuf, ln2_s + l * Dv, ln2_b + l * Dv);
        gemm_mfma<1, 1><<<dim3(Fv / 128, GM), 256, 0, stream>>>(
            abuf, wf, fc_b + (size_t)l * Fv, nullptr, hbuf, TOK, Fv, Dv);
        gemm_mfma<0, 0><<<dim3(Dv / 128, GM), 256, 0, stream>>>(
            hbuf, wp, proj_b + (size_t)l * Dv, x, x, TOK, Dv, Fv);
    }

    head_kernel<<<Bv, 256, 0, stream>>>(x, lnpost_s, lnpost_b, vis_proj, out);
}

// Round 4
// 4336.934 us; speedup vs baseline: 6.9179x; 1.9242x over previous
//
#include <hip/hip_runtime.h>
#include <cstddef>

#define Bv   32
#define Sv   197
#define Dv   768
#define Hh   12
#define HDv  64
#define Fv   3072
#define Lv   12
#define Ov   512
#define TOK  (Bv * Sv)        // 6304
#define MPAD 6400             // TOK padded to multiple of 128
#define NPATCH 196
#define CONV_M (Bv * NPATCH)  // 6272 (multiple of 128 exactly: 49*128)

#define WQ_SZ (2304 * 768)
#define WO_SZ (768 * 768)
#define WF_SZ (3072 * 768)
#define WP_SZ (768 * 3072)
#define WTOT  (WQ_SZ + WO_SZ + WF_SZ + WP_SZ)   // 7077888

typedef __attribute__((ext_vector_type(8))) __bf16 bf16x8;
typedef __attribute__((ext_vector_type(4))) float f32x4;

__device__ __forceinline__ unsigned short f2bf(float f) {
    unsigned int u = __float_as_uint(f);
    unsigned int r = (u + 0x7fffu + ((u >> 16) & 1u)) >> 16;
    return (unsigned short)r;
}

__device__ __forceinline__ void async_ld16(const void* g, void* l) {
    __builtin_amdgcn_global_load_lds(
        (__attribute__((address_space(1))) void*)(g),
        (__attribute__((address_space(3))) void*)(l),
        16, 0, 0);
}

// ---------------------------------------------------------------------------
// block-wide (256 thread) reduction of two scalars
// ---------------------------------------------------------------------------
__device__ __forceinline__ void reduce2_256(float& s1, float& s2) {
    #pragma unroll
    for (int off = 32; off > 0; off >>= 1) {
        s1 += __shfl_down(s1, off, 64);
        s2 += __shfl_down(s2, off, 64);
    }
    __shared__ float r1[4], r2[4];
    int lane = threadIdx.x & 63, w = threadIdx.x >> 6;
    if (lane == 0) { r1[w] = s1; r2[w] = s2; }
    __syncthreads();
    s1 = r1[0] + r1[1] + r1[2] + r1[3];
    s2 = r2[0] + r2[1] + r2[2] + r2[3];
    __syncthreads();
}

// ---------------------------------------------------------------------------
// weight fp32 -> bf16 conversion
// ---------------------------------------------------------------------------
__global__ void convert_kernel(const float* __restrict__ src,
                               unsigned short* __restrict__ dst, int n4) {
    int gid = blockIdx.x * 256 + threadIdx.x;
    if (gid >= n4) return;
    int idx = gid * 4;
    float4 v = *(const float4*)(src + idx);
    ushort4 r = make_ushort4(f2bf(v.x), f2bf(v.y), f2bf(v.z), f2bf(v.w));
    *(ushort4*)(dst + idx) = r;
}

__global__ void convertw_kernel(const float* __restrict__ wq,
                                const float* __restrict__ wo,
                                const float* __restrict__ wf,
                                const float* __restrict__ wp,
                                unsigned short* __restrict__ dst) {
    int idx = (blockIdx.x * 256 + threadIdx.x) * 4;
    const float* s; int off;
    if (idx < WQ_SZ)                     { s = wq; off = idx; }
    else if (idx < WQ_SZ + WO_SZ)        { s = wo; off = idx - WQ_SZ; }
    else if (idx < WQ_SZ + WO_SZ + WF_SZ){ s = wf; off = idx - WQ_SZ - WO_SZ; }
    else                                 { s = wp; off = idx - WQ_SZ - WO_SZ - WF_SZ; }
    float4 v = *(const float4*)(s + off);
    ushort4 r = make_ushort4(f2bf(v.x), f2bf(v.y), f2bf(v.z), f2bf(v.w));
    *(ushort4*)(dst + idx) = r;
}

// ---------------------------------------------------------------------------
// im2col + normalize -> bf16 patches [6272, 768]
// ---------------------------------------------------------------------------
__global__ void im2col_kernel(const float* __restrict__ img,
                              unsigned short* __restrict__ out) {
    int idx = blockIdx.x * 256 + threadIdx.x;
    int col = idx % 768;
    int row = idx / 768;
    int b = row / NPATCH, p = row % NPATCH;
    int ph = p / 14, pw = p % 14;
    int c  = col >> 8;
    int r  = col & 255;
    int kh = r >> 4, kw = r & 15;
    int y = ph * 16 + kh, x = pw * 16 + kw;
    const float mean[3] = {0.48145466f, 0.4578275f, 0.40821073f};
    const float stdv[3] = {0.26862954f, 0.26130258f, 0.27577711f};
    float v = img[((size_t)(b * 3 + c) * 224 + y) * 224 + x];
    out[idx] = f2bf((v - mean[c]) / stdv[c]);
}

// ---------------------------------------------------------------------------
// MFMA bf16 GEMM: C[m,n] = sum_k A[m,k]*W[n,k] (+bias) (+res fp32) (QuickGELU)
// 128x128 tile, BK=32, 256 threads (4 waves, each 64x64 quadrant).
// ---------------------------------------------------------------------------
template<int ODT, int ACT>
__global__ __launch_bounds__(256) void gemm_mfma(
        const unsigned short* __restrict__ A, const unsigned short* __restrict__ W,
        const float* __restrict__ bias, const float* __restrict__ res,
        void* __restrict__ Cv, int M, int N, int K)
{
    __shared__ unsigned short As[128 * 32];
    __shared__ unsigned short Ws[128 * 32];
    const int tid = threadIdx.x;
    const int w = tid >> 6, l = tid & 63;
    const int m0 = blockIdx.y << 7, n0 = blockIdx.x << 7;

    const int srow = w * 32 + (l >> 2);
    const int scol = (l & 3) * 8;
    const unsigned short* ag0 = A + (size_t)(m0 + srow) * K + scol;
    const unsigned short* ag1 = ag0 + (size_t)16 * K;
    const unsigned short* wg0 = W + (size_t)(n0 + srow) * K + scol;
    const unsigned short* wg1 = wg0 + (size_t)16 * K;
    unsigned short* al0 = As + w * 1024;
    unsigned short* al1 = As + w * 1024 + 512;
    unsigned short* wl0 = Ws + w * 1024;
    unsigned short* wl1 = Ws + w * 1024 + 512;

    const int wm = w >> 1, wn = w & 1;
    const int fr = l & 15, fq = l >> 4;
    const unsigned short* afp[4];
    const unsigned short* wfp[4];
    #pragma unroll
    for (int i = 0; i < 4; i++) {
        afp[i] = As + (wm * 64 + i * 16 + fr) * 32 + fq * 8;
        wfp[i] = Ws + (wn * 64 + i * 16 + fr) * 32 + fq * 8;
    }

    f32x4 acc[4][4] = {};

    const int nk = K >> 5;
    for (int kk = 0; kk < nk; kk++) {
        const int ko = kk << 5;
        __syncthreads();
        async_ld16(ag0 + ko, al0);
        async_ld16(ag1 + ko, al1);
        async_ld16(wg0 + ko, wl0);
        async_ld16(wg1 + ko, wl1);
        __syncthreads();
        bf16x8 af[4], wf[4];
        #pragma unroll
        for (int i = 0; i < 4; i++) {
            af[i] = *(const bf16x8*)afp[i];
            wf[i] = *(const bf16x8*)wfp[i];
        }
        #pragma unroll
        for (int i = 0; i < 4; i++) {
            #pragma unroll
            for (int j = 0; j < 4; j++) {
                acc[i][j] = __builtin_amdgcn_mfma_f32_16x16x32_bf16(
                    af[i], wf[j], acc[i][j], 0, 0, 0);
            }
        }
    }

    float bn[4];
    #pragma unroll
    for (int j = 0; j < 4; j++)
        bn[j] = bias ? bias[n0 + wn * 64 + j * 16 + fr] : 0.f;

    #pragma unroll
    for (int i = 0; i < 4; i++) {
        #pragma unroll
        for (int r = 0; r < 4; r++) {
            int m = m0 + wm * 64 + i * 16 + fq * 4 + r;
            if (m < M) {
                size_t rowb = (size_t)m * N;
                #pragma unroll
                for (int j = 0; j < 4; j++) {
                    int n = n0 + wn * 64 + j * 16 + fr;
                    float v = acc[i][j][r] + bn[j];
                    if (res) v += res[rowb + n];
                    if (ACT) v = v / (1.f + __expf(-1.702f * v));
                    if (ODT == 0) ((float*)Cv)[rowb + n] = v;
                    else ((unsigned short*)Cv)[rowb + n] = f2bf(v);
                }
            }
        }
    }
}

// ---------------------------------------------------------------------------
// LayerNorm fp32 in -> bf16 out. One block per token.
// ---------------------------------------------------------------------------
__global__ void ln_kernel(const float* __restrict__ in, unsigned short* __restrict__ out,
                          const float* __restrict__ s, const float* __restrict__ b) {
    int t = blockIdx.x;
    const float* row = in + (size_t)t * Dv;
    int tid = threadIdx.x;
    float v[3], s1 = 0.f, s2 = 0.f;
    #pragma unroll
    for (int i = 0; i < 3; i++) {
        v[i] = row[tid + 256 * i];
        s1 += v[i]; s2 += v[i] * v[i];
    }
    reduce2_256(s1, s2);
    float mean = s1 * (1.0f / Dv);
    float var  = s2 * (1.0f / Dv) - mean * mean;
    float rstd = rsqrtf(var + 1e-5f);
    unsigned short* orow = out + (size_t)t * Dv;
    #pragma unroll
    for (int i = 0; i < 3; i++) {
        int d = tid + 256 * i;
        orow[d] = f2bf((v[i] - mean) * rstd * s[d] + b[d]);
    }
}

// ---------------------------------------------------------------------------
// embed (cls/patch + pos) + ln_pre -> x fp32. One block per token.
// ---------------------------------------------------------------------------
__global__ void embed_ln_kernel(const float* __restrict__ conv_out,
                                const float* __restrict__ cls,
                                const float* __restrict__ pos,
                                const float* __restrict__ s,
                                const float* __restrict__ b,
                                float* __restrict__ x) {
    int t = blockIdx.x;
    int bb = t / Sv, si = t % Sv;
    int tid = threadIdx.x;
    float v[3], s1 = 0.f, s2 = 0.f;
    #pragma unroll
    for (int i = 0; i < 3; i++) {
        int d = tid + 256 * i;
        float e = (si == 0) ? cls[d]
                            : conv_out[((size_t)bb * NPATCH + (si - 1)) * Dv + d];
        v[i] = e + pos[(size_t)si * Dv + d];
        s1 += v[i]; s2 += v[i] * v[i];
    }
    reduce2_256(s1, s2);
    float mean = s1 * (1.0f / Dv);
    float var  = s2 * (1.0f / Dv) - mean * mean;
    float rstd = rsqrtf(var + 1e-5f);
    float* orow = x + (size_t)t * Dv;
    #pragma unroll
    for (int i = 0; i < 3; i++) {
        int d = tid + 256 * i;
        orow[d] = (v[i] - mean) * rstd * s[d] + b[d];
    }
}

// ---------------------------------------------------------------------------
// Attention v4 (MFMA): grid (7, H, B); block = 256 thr = 4 waves; 32 q-rows.
// QK^T: Q A-frags + K B-frags straight from global (K rows are B layout).
// Scores in C-layout regs; softmax via shfl + LDS cross-wave combine;
// P bf16 -> LDS in A layout (cols >=197 exactly zero). PV: V^T staged in
// LDS (zero-padded); wave w computes output dims [w*16, w*16+16).
// qkv bf16 [TOK,2304] packed q|k|v each [12,64]; out bf16 [TOK,768].
// ---------------------------------------------------------------------------
__global__ __launch_bounds__(256) void attn4_kernel(
        const unsigned short* __restrict__ qkv, unsigned short* __restrict__ o) {
    const int qg = blockIdx.x, h = blockIdx.y, b = blockIdx.z;
    __shared__ __align__(16) unsigned short vt[64][232];   // V^T [d][j], 29.7 KB
    __shared__ __align__(16) unsigned short pb[32][236];   // P bf16 [row][k], 14.8 KB
    __shared__ float red[4][32];
    __shared__ float smax_f[32];
    __shared__ float sinv_f[32];

    const int tid = threadIdx.x;
    const int w = tid >> 6, l = tid & 63;
    const int fr = l & 15, fq = l >> 4;
    const size_t base = (size_t)b * Sv;
    const unsigned int* q32 = (const unsigned int*)qkv;    // row stride 1152 uints

    // ---- stage V^T (cols >= 197 zeroed) ----
    for (int i = tid; i < 224 * 32; i += 256) {
        int j = i >> 5, u = i & 31;
        unsigned int val = (j < Sv) ? q32[(base + j) * 1152 + 768 + h * 32 + u] : 0u;
        vt[2 * u][j]     = (unsigned short)(val & 0xffffu);
        vt[2 * u + 1][j] = (unsigned short)(val >> 16);
    }

    union U { uint4 u; bf16x8 v; };

    // ---- QK^T: sc[mt][s], rows qg*32+mt*16+fq*4+r, cols (w+4s)*16+fr ----
    f32x4 sc[2][4] = {};
    #pragma unroll
    for (int ks = 0; ks < 2; ks++) {
        U aq[2];
        #pragma unroll
        for (int mt = 0; mt < 2; mt++) {
            int row = qg * 32 + mt * 16 + fr;
            int rc = row < Sv ? row : Sv - 1;
            aq[mt].u = *(const uint4*)(qkv + (base + rc) * 2304 + h * 64 + ks * 32 + fq * 8);
        }
        #pragma unroll
        for (int s = 0; s < 4; s++) {
            int nt = w + 4 * s;
            if (nt >= 14) continue;
            int col = nt * 16 + fr;
            int cc = col < Sv ? col : Sv - 1;
            U bq;
            bq.u = *(const uint4*)(qkv + (base + cc) * 2304 + 768 + h * 64 + ks * 32 + fq * 8);
            #pragma unroll
            for (int mt = 0; mt < 2; mt++)
                sc[mt][s] = __builtin_amdgcn_mfma_f32_16x16x32_bf16(
                    aq[mt].v, bq.v, sc[mt][s], 0, 0, 0);
        }
    }

    // ---- scale + mask + row max ----
    float rmax[2][4];
    #pragma unroll
    for (int mt = 0; mt < 2; mt++)
        #pragma unroll
        for (int r = 0; r < 4; r++) rmax[mt][r] = -1e30f;
    #pragma unroll
    for (int mt = 0; mt < 2; mt++) {
        #pragma unroll
        for (int s = 0; s < 4; s++) {
            int nt = w + 4 * s;
            int col = nt * 16 + fr;
            bool valid = (nt < 14) && (col < Sv);
            #pragma unroll
            for (int r = 0; r < 4; r++) {
                float v = valid ? sc[mt][s][r] * 0.125f : -1e30f;
                sc[mt][s][r] = v;
                rmax[mt][r] = fmaxf(rmax[mt][r], v);
            }
        }
    }
    #pragma unroll
    for (int mt = 0; mt < 2; mt++) {
        #pragma unroll
        for (int r = 0; r < 4; r++) {
            float m = rmax[mt][r];
            m = fmaxf(m, __shfl_xor(m, 1, 64));
            m = fmaxf(m, __shfl_xor(m, 2, 64));
            m = fmaxf(m, __shfl_xor(m, 4, 64));
            m = fmaxf(m, __shfl_xor(m, 8, 64));
            rmax[mt][r] = m;
        }
    }
    if (fr == 0) {
        #pragma unroll
        for (int mt = 0; mt < 2; mt++)
            #pragma unroll
            for (int r = 0; r < 4; r++)
                red[w][mt * 16 + fq * 4 + r] = rmax[mt][r];
    }
    __syncthreads();
    if (tid < 32)
        smax_f[tid] = fmaxf(fmaxf(red[0][tid], red[1][tid]),
                            fmaxf(red[2][tid], red[3][tid]));
    __syncthreads();

    // ---- exp + row sum + write P (bf16, A layout) ----
    float rsum[2][4] = {};
    #pragma unroll
    for (int mt = 0; mt < 2; mt++) {
        float fm[4];
        #pragma unroll
        for (int r = 0; r < 4; r++) fm[r] = smax_f[mt * 16 + fq * 4 + r];
        #pragma unroll
        for (int s = 0; s < 4; s++) {
            int nt = w + 4 * s;
            if (nt >= 14) continue;
            int col = nt * 16 + fr;
            #pragma unroll
            for (int r = 0; r < 4; r++) {
                float p = (col < Sv) ? __expf(sc[mt][s][r] - fm[r]) : 0.f;
                rsum[mt][r] += p;
                pb[mt * 16 + fq * 4 + r][col] = f2bf(p);
            }
        }
    }
    #pragma unroll
    for (int mt = 0; mt < 2; mt++) {
        #pragma unroll
        for (int r = 0; r < 4; r++) {
            float s = rsum[mt][r];
            s += __shfl_xor(s, 1, 64);
            s += __shfl_xor(s, 2, 64);
            s += __shfl_xor(s, 4, 64);
            s += __shfl_xor(s, 8, 64);
            rsum[mt][r] = s;
        }
    }
    if (fr == 0) {
        #pragma unroll
        for (int mt = 0; mt < 2; mt++)
            #pragma unroll
            for (int r = 0; r < 4; r++)
                red[w][mt * 16 + fq * 4 + r] = rsum[mt][r];
    }
    __syncthreads();
    if (tid < 32)
        sinv_f[tid] = 1.f / (red[0][tid] + red[1][tid] + red[2][tid] + red[3][tid]);
    __syncthreads();   // also guarantees vt + pb staging complete

    // ---- PV: wave w -> output dims [w*16, w*16+16) ----
    f32x4 oc[2] = {};
    #pragma unroll
    for (int ks = 0; ks < 7; ks++) {
        U bv;
        bv.u = *(const uint4*)&vt[w * 16 + fr][ks * 32 + fq * 8];
        #pragma unroll
        for (int mt = 0; mt < 2; mt++) {
            const unsigned short* ap = &pb[mt * 16 + fr][ks * 32 + fq * 8];
            uint2 lo = *(const uint2*)ap;
            uint2 hi = *(const uint2*)(ap + 4);
            U a; a.u = make_uint4(lo.x, lo.y, hi.x, hi.y);
            oc[mt] = __builtin_amdgcn_mfma_f32_16x16x32_bf16(a.v, bv.v, oc[mt], 0, 0, 0);
        }
    }

    // ---- epilogue: /= rowsum, store bf16 ----
    #pragma unroll
    for (int mt = 0; mt < 2; mt++) {
        #pragma unroll
        for (int r = 0; r < 4; r++) {
            int lrow = mt * 16 + fq * 4 + r;
            int row = qg * 32 + lrow;
            if (row < Sv)
                o[(base + row) * Dv + h * 64 + w * 16 + fr] =
                    f2bf(oc[mt][r] * sinv_f[lrow]);
        }
    }
}

// ---------------------------------------------------------------------------
// Head: ln_post on cls token + @ vis_proj [768,512] fp32. One block per batch.
// ---------------------------------------------------------------------------
__global__ void head_kernel(const float* __restrict__ x,
                            const float* __restrict__ s, const float* __restrict__ b,
                            const float* __restrict__ vp, float* __restrict__ out) {
    int bb = blockIdx.x, tid = threadIdx.x;
    __shared__ float xn[Dv];
    const float* row = x + (size_t)(bb * Sv) * Dv;
    float v[3], s1 = 0.f, s2 = 0.f;
    #pragma unroll
    for (int i = 0; i < 3; i++) {
        v[i] = row[tid + 256 * i];
        s1 += v[i]; s2 += v[i] * v[i];
    }
    reduce2_256(s1, s2);
    float mean = s1 * (1.0f / Dv);
    float var  = s2 * (1.0f / Dv) - mean * mean;
    float rstd = rsqrtf(var + 1e-5f);
    #pragma unroll
    for (int i = 0; i < 3; i++) {
        int d = tid + 256 * i;
        xn[d] = (v[i] - mean) * rstd * s[d] + b[d];
    }
    __syncthreads();
    float acc0 = 0.f, acc1 = 0.f;
    for (int d = 0; d < Dv; d++) {
        float xv = xn[d];
        acc0 += xv * vp[(size_t)d * Ov + tid];
        acc1 += xv * vp[(size_t)d * Ov + tid + 256];
    }
    out[(size_t)bb * Ov + tid]       = acc0;
    out[(size_t)bb * Ov + tid + 256] = acc1;
}

// ---------------------------------------------------------------------------
extern "C" void kernel_launch(void* const* d_in, const int* in_sizes, int n_in,
                              void* d_out, int out_size, void* d_ws, size_t ws_size,
                              hipStream_t stream) {
    const float* images   = (const float*)d_in[0];
    const float* conv_w   = (const float*)d_in[1];
    const float* cls_emb  = (const float*)d_in[2];
    const float* pos_emb  = (const float*)d_in[3];
    const float* lnpre_s  = (const float*)d_in[4];
    const float* lnpre_b  = (const float*)d_in[5];
    const float* ln1_s    = (const float*)d_in[6];
    const float* ln1_b    = (const float*)d_in[7];
    const float* qkv_w    = (const float*)d_in[8];
    const float* qkv_b    = (const float*)d_in[9];
    const float* out_w    = (const float*)d_in[10];
    const float* out_b    = (const float*)d_in[11];
    const float* ln2_s    = (const float*)d_in[12];
    const float* ln2_b    = (const float*)d_in[13];
    const float* fc_w     = (const float*)d_in[14];
    const float* fc_b     = (const float*)d_in[15];
    const float* proj_w   = (const float*)d_in[16];
    const float* proj_b   = (const float*)d_in[17];
    const float* lnpost_s = (const float*)d_in[18];
    const float* lnpost_b = (const float*)d_in[19];
    const float* vis_proj = (const float*)d_in[20];
    float* out = (float*)d_out;

    char* p = (char*)d_ws;
    float* x              = (float*)p;          p += (size_t)TOK * Dv * 4;       // 19.4 MB
    unsigned short* abuf  = (unsigned short*)p; p += (size_t)MPAD * Dv * 2;      //  9.8 MB
    unsigned short* qkvb  = (unsigned short*)p; p += (size_t)MPAD * 2304 * 2;    // 29.5 MB
    unsigned short* hbuf  = (unsigned short*)p; p += (size_t)MPAD * Fv * 2;      // 39.3 MB
    unsigned short* wbuf  = (unsigned short*)p; p += (size_t)WTOT * 2;           // 14.2 MB
    unsigned short* cwb   = (unsigned short*)p; p += (size_t)WO_SZ * 2;          //  1.2 MB
    // aliases (pre-loop only):
    unsigned short* im2c  = qkvb;               // [6272,768] bf16
    float* convo          = (float*)hbuf;       // [6272,768] fp32

    // patch embedding
    convert_kernel<<<WO_SZ / 4 / 256, 256, 0, stream>>>(conv_w, cwb, WO_SZ / 4);
    im2col_kernel<<<(CONV_M * Dv) / 256, 256, 0, stream>>>(images, im2c);
    gemm_mfma<0, 0><<<dim3(Dv / 128, CONV_M / 128), 256, 0, stream>>>(
        im2c, cwb, nullptr, nullptr, convo, CONV_M, Dv, Dv);
    embed_ln_kernel<<<TOK, 256, 0, stream>>>(convo, cls_emb, pos_emb,
                                             lnpre_s, lnpre_b, x);

    unsigned short* wq = wbuf;
    unsigned short* wo = wbuf + WQ_SZ;
    unsigned short* wf = wbuf + WQ_SZ + WO_SZ;
    unsigned short* wp = wbuf + WQ_SZ + WO_SZ + WF_SZ;
    const int GM = MPAD / 128;   // 50

    for (int l = 0; l < Lv; l++) {
        convertw_kernel<<<WTOT / 4 / 256, 256, 0, stream>>>(
            qkv_w + (size_t)l * WQ_SZ, out_w + (size_t)l * WO_SZ,
            fc_w + (size_t)l * WF_SZ, proj_w + (size_t)l * WP_SZ, wbuf);
        ln_kernel<<<TOK, 256, 0, stream>>>(x, abuf, ln1_s + l * Dv, ln1_b + l * Dv);
        gemm_mfma<1, 0><<<dim3(2304 / 128, GM), 256, 0, stream>>>(
            abuf, wq, qkv_b + (size_t)l * 2304, nullptr, qkvb, TOK, 2304, Dv);
        attn4_kernel<<<dim3(7, Hh, Bv), 256, 0, stream>>>(qkvb, abuf);
        gemm_mfma<0, 0><<<dim3(Dv / 128, GM), 256, 0, stream>>>(
            abuf, wo, out_b + (size_t)l * Dv, x, x, TOK, Dv, Dv);
        ln_kernel<<<TOK, 256, 0, stream>>>(x, abuf, ln2_s + l * Dv, ln2_b + l * Dv);
        gemm_mfma<1, 1><<<dim3(Fv / 128, GM), 256, 0, stream>>>(
            abuf, wf, fc_b + (size_t)l * Fv, nullptr, hbuf, TOK, Fv, Dv);
        gemm_mfma<0, 0><<<dim3(Dv / 128, GM), 256, 0, stream>>>(
            hbuf, wp, proj_b + (size_t)l * Dv, x, x, TOK, Dv, Fv);
    }

    head_kernel<<<Bv, 256, 0, stream>>>(x, lnpost_s, lnpost_b, vis_proj, out);
}